// Round 4
// baseline (124.612 us; speedup 1.0000x reference)
//
#include <hip/hip_runtime.h>

// Performer causal linear attention (generalized relu kernel), fp32 in/out.
// B=1, H=8, N=1024, D=64, M=128. Sub-block formulation, S=32 rows/block:
//   qp = relu(norm * q @ proj^T) + eps ; kp likewise
//   Z  = cumsum_n kp ; W = qp / Z
//   out_s = W_s @ S0_s + tril(W_s @ Kp_s^T) @ V_s ; S0_s = prefix of Kp^T V
// R16: fuse the three R15 kernels into ONE 256-block kernel with two manual
// device-scope grid barriers (release fence + atomicAdd arrive, relaxed
// agent-scope poll + acquire fence). 256 blocks x 512 thr x 60.4KB LDS =
// guaranteed co-resident (capacity 2 blocks/CU), so no deadlock. Barrier
// counters in d_ws[0..64), zeroed each iteration by hipMemsetAsync (stream-
// ordered, graph-capture-safe). Phase bodies are verbatim R15; phase 2
// remapped to 256 blocks / 1 chain per thread with identical fp32 chain
// order (bit-identical output). Removes 2 launch/drain boundaries.
static constexpr int H = 8, N = 1024, D = 64, M = 128;
static constexpr unsigned NBLK = 256;
static constexpr float EPS = 1e-3f;
static constexpr float NORM = 0.35355339059327373f; // 64^-0.25

typedef __attribute__((ext_vector_type(8))) short short8;
typedef __attribute__((ext_vector_type(4))) float f32x4;

__device__ inline unsigned short f2bf(float x) {
    unsigned u = __float_as_uint(x);
    return (unsigned short)((u + 0x7fffu + ((u >> 16) & 1u)) >> 16);
}
__device__ inline float bf2f(unsigned short u) {
    return __uint_as_float(((unsigned)u) << 16);
}
__device__ inline ushort4 pack4(float4 g) {
    return (ushort4){f2bf(g.x), f2bf(g.y), f2bf(g.z), f2bf(g.w)};
}

// Device-scope grid barrier. Safe only because grid (256) <= co-resident
// capacity. Release: __threadfence (agent fence -> L2 writeback) before
// arrive; acquire: relaxed poll then __threadfence (-> L2 inv) after.
__device__ inline void grid_barrier(unsigned* cnt) {
    __syncthreads();
    if (threadIdx.x == 0) {
        __threadfence();
        atomicAdd(cnt, 1u); // device-scope by default on gfx950
        while (__hip_atomic_load(cnt, __ATOMIC_RELAXED,
                                 __HIP_MEMORY_SCOPE_AGENT) < NBLK) {
            __builtin_amdgcn_s_sleep(2);
        }
        __threadfence();
    }
    __syncthreads();
}

__global__ __launch_bounds__(512) void k_fused(
    const float* __restrict__ q, const float* __restrict__ k,
    const float* __restrict__ proj, const float* __restrict__ v,
    unsigned short* __restrict__ qpb, unsigned short* __restrict__ kpb,
    unsigned short* __restrict__ Gpb, float* __restrict__ kpart,
    float* __restrict__ zpre, unsigned short* __restrict__ S0pre,
    float* __restrict__ out, unsigned* __restrict__ bar) {
    __shared__ __align__(16) short smem[30208]; // 60.4 KB (phase-1 size)
    const int tid = threadIdx.x;
    const int b = blockIdx.x;

    // ================= phase 1: proj + G + kpart (R15 k_projg) ============
    {
        short* projb = smem;         // [m 128][72] B-operand
        short* xb = smem + 9216;     // [r 64][72] A-operand (q 0-31, k 32-63)
        short* obuf = smem + 13824;  // [64][136] out tile / later [128][68] G
        short* kpT = smem + 22528;   // [m 128][40] A-operand for G
        short* vT = smem + 27648;    // [e 64][40] B-operand for G
        const int rblk = b & 31;
        const int h = b >> 5;
        const int rowbase = h * N + rblk * 32;
        const int lane = tid & 63, wv = tid >> 6;
        const int rt = wv & 3, mh = wv >> 2;
        const int fr = lane & 15, fq = lane >> 4;

        for (int i4 = tid; i4 < 2048; i4 += 512) {
            int m = i4 >> 4, dq = i4 & 15;
            *(ushort4*)&projb[m * 72 + dq * 4] =
                pack4(*(const float4*)&proj[i4 * 4]);
        }
        {
            int r = tid >> 4, dq = tid & 15;
            float4 g = *(const float4*)&q[(rowbase + r) * D + dq * 4];
            g.x *= NORM; g.y *= NORM; g.z *= NORM; g.w *= NORM;
            *(ushort4*)&xb[r * 72 + dq * 4] = pack4(g);
            float4 gk = *(const float4*)&k[(rowbase + r) * D + dq * 4];
            gk.x *= NORM; gk.y *= NORM; gk.z *= NORM; gk.w *= NORM;
            *(ushort4*)&xb[(32 + r) * 72 + dq * 4] = pack4(gk);
            int rv = tid & 31, e4 = (tid >> 5) * 4;
            float4 gv = *(const float4*)&v[(rowbase + rv) * D + e4];
            vT[(e4 + 0) * 40 + rv] = (short)f2bf(gv.x);
            vT[(e4 + 1) * 40 + rv] = (short)f2bf(gv.y);
            vT[(e4 + 2) * 40 + rv] = (short)f2bf(gv.z);
            vT[(e4 + 3) * 40 + rv] = (short)f2bf(gv.w);
        }
        __syncthreads();

        f32x4 accp[4];
#pragma unroll
        for (int i = 0; i < 4; i++) accp[i] = (f32x4){0.f, 0.f, 0.f, 0.f};
#pragma unroll
        for (int kt = 0; kt < 2; kt++) {
            short8 a = *(const short8*)&xb[(16 * rt + fr) * 72 + kt * 32 + fq * 8];
#pragma unroll
            for (int i = 0; i < 4; i++) {
                const int mt = mh * 4 + i;
                short8 bb =
                    *(const short8*)&projb[(16 * mt + fr) * 72 + kt * 32 + fq * 8];
                accp[i] =
                    __builtin_amdgcn_mfma_f32_16x16x32_bf16(a, bb, accp[i], 0, 0, 0);
            }
        }
#pragma unroll
        for (int i = 0; i < 4; i++) {
            const int mt = mh * 4 + i;
#pragma unroll
            for (int reg = 0; reg < 4; reg++) {
                const int r = 16 * rt + fq * 4 + reg;
                const int m = 16 * mt + fr;
                unsigned short bv = f2bf(fmaxf(accp[i][reg], 0.f) + EPS);
                obuf[r * 136 + m] = (short)bv;
                if (rt >= 2) kpT[m * 40 + (r - 32)] = (short)bv;
            }
        }
        __syncthreads();

        for (int i = tid; i < 2048; i += 512) {
            int r = i >> 5, cu = i & 31;
            ushort4 val = *(const ushort4*)&obuf[r * 136 + cu * 4];
            unsigned short* g = (r < 32) ? &qpb[(rowbase + r) * M + cu * 4]
                                         : &kpb[(rowbase + r - 32) * M + cu * 4];
            *(ushort4*)g = val;
        }
        const int gb = h * 32 + rblk;
        if (tid < 128) {
            float ks = 0.f;
#pragma unroll 8
            for (int r = 0; r < 32; r++)
                ks += bf2f((unsigned short)kpT[tid * 40 + r]);
            kpart[gb * M + tid] = ks;
        }
        __syncthreads();

        f32x4 gacc[4];
#pragma unroll
        for (int et = 0; et < 4; et++) gacc[et] = (f32x4){0.f, 0.f, 0.f, 0.f};
        {
            short8 a = *(const short8*)&kpT[(16 * wv + fr) * 40 + fq * 8];
#pragma unroll
            for (int et = 0; et < 4; et++) {
                short8 bb = *(const short8*)&vT[(16 * et + fr) * 40 + fq * 8];
                gacc[et] =
                    __builtin_amdgcn_mfma_f32_16x16x32_bf16(a, bb, gacc[et], 0, 0, 0);
            }
        }
#pragma unroll
        for (int et = 0; et < 4; et++)
#pragma unroll
            for (int reg = 0; reg < 4; reg++) {
                const int m = 16 * wv + fq * 4 + reg;
                obuf[m * 68 + 16 * et + fr] = (short)f2bf(gacc[et][reg]);
            }
        __syncthreads();
        for (int i = tid; i < 2048; i += 512) {
            int m = i >> 4, e4 = (i & 15) * 4;
            *(ushort4*)&Gpb[(gb * M + m) * D + e4] =
                *(const ushort4*)&obuf[m * 68 + e4];
        }
    }
    grid_barrier(&bar[0]); // Gpb, kpart, qpb, kpb ready device-wide

    // ================= phase 2: s-granular prefixes (R15 k_prefix) ========
    // 256 blocks: (h = b>>5, seg = b&31); tid<256 each own one (m,e) chain.
    // Same fp32 chain order as R15 -> bit-identical S0pre/zpre.
    {
        const int h = b >> 5, seg = b & 31;
        if (tid < 256) {
            const int eb = seg * 256 + tid;
            float a = 0.f;
#pragma unroll 8
            for (int s = 0; s < 32; s++) {
                S0pre[(h * 32 + s) * (M * D) + eb] = f2bf(a);
                a += bf2f(Gpb[(h * 32 + s) * (M * D) + eb]);
            }
        }
        if (seg == 0 && tid < 128) {
            float z = 0.f;
#pragma unroll 8
            for (int s = 0; s < 32; s++) {
                zpre[(h * 32 + s) * M + tid] = z;
                z += kpart[(h * 32 + s) * M + tid];
            }
        }
    }
    grid_barrier(&bar[1]); // S0pre, zpre ready device-wide

    // ================= phase 3: attention (R15 k_attn) ====================
    {
        short* bufW = smem;          // W  [32 n][136]
        short* bufK = smem + 4352;   // Kp [32 j][136]
        short* bufQ = smem + 8704;   // qp [32 n][136]
        short* s0t = smem + 13056;   // S0^T [64 e][136] (m in columns)
        short* vT = smem + 21760;    // V^T  [64 e][40]  (j in columns)
        short* bufP = smem + 24320;  // Pb   [32 n][40]  (j in columns)
        const int h = b >> 5, s = b & 31;
        const int rowstart = h * N + s * 32;
        const int lane = tid & 63, wv = tid >> 6;
        const int rt = wv & 1, js = wv >> 1;
        const int fr = lane & 15, fq = lane >> 4;

        // ---- stage Kp + qp own rows (coalesced uint loads)
        {
            const unsigned int* srck = (const unsigned int*)kpb;
            const unsigned int* srcq = (const unsigned int*)qpb;
            for (int i = tid; i < 2048; i += 512) {
                int j = i >> 6, mu = i & 63;
                ((unsigned int*)&bufK[j * 136])[mu] =
                    srck[(rowstart + j) * 64 + mu];
                ((unsigned int*)&bufQ[j * 136])[mu] =
                    srcq[(rowstart + j) * 64 + mu];
            }
        }
        // ---- stage S0^T (16 bf16/thread, coalesced 32B)
        {
            const int pm = tid >> 2, peb = (tid & 3) * 16;
            const unsigned short* src =
                &S0pre[(h * 32 + s) * (M * D) + pm * D + peb];
            short8 s0a = *(const short8*)&src[0];
            short8 s0b = *(const short8*)&src[8];
#pragma unroll
            for (int j = 0; j < 8; j++) {
                s0t[(peb + j) * 136 + pm] = s0a[j];
                s0t[(peb + 8 + j) * 136 + pm] = s0b[j];
            }
        }
        // ---- stage V^T (fp32 -> bf16), own 32 rows
        {
            const int j = tid >> 4, e4 = (tid & 15) * 4;
            float4 gv = *(const float4*)&v[(rowstart + j) * D + e4];
            vT[(e4 + 0) * 40 + j] = (short)f2bf(gv.x);
            vT[(e4 + 1) * 40 + j] = (short)f2bf(gv.y);
            vT[(e4 + 2) * 40 + j] = (short)f2bf(gv.z);
            vT[(e4 + 3) * 40 + j] = (short)f2bf(gv.w);
        }
        float zinit = 0.f;
        if (tid < 128) zinit = zpre[(h * 32 + s) * M + tid];
        __syncthreads(); // (1)

        // ---- z-scan -> W (tid<128, seeded from zpre)
        if (tid < 128) {
            const int m = tid;
            float z = zinit;
#pragma unroll 8
            for (int r = 0; r < 32; r++) {
                z += bf2f((unsigned short)bufK[r * 136 + m]);
                bufW[r * 136 + m] = (short)f2bf(
                    bf2f((unsigned short)bufQ[r * 136 + m]) *
                    __builtin_amdgcn_rcpf(z));
            }
        }
        __syncthreads(); // (2) W ready

        // ---- P2a: out = W @ S0 (K=128) — all 8 waves, tile (rt, js)
        f32x4 acc2 = (f32x4){0.f, 0.f, 0.f, 0.f};
#pragma unroll
        for (int kt = 0; kt < 4; kt++) {
            short8 a = *(const short8*)&bufW[(16 * rt + fr) * 136 + kt * 32 + fq * 8];
            short8 bb = *(const short8*)&s0t[(16 * js + fr) * 136 + kt * 32 + fq * 8];
            acc2 = __builtin_amdgcn_mfma_f32_16x16x32_bf16(a, bb, acc2, 0, 0, 0);
        }
        // ---- P1: Pb = tril(W @ Kp^T) — waves 0..3 only, tile (rt, jt)
        if (wv < 4) {
            const int jt = wv >> 1;
            f32x4 acc1 = (f32x4){0.f, 0.f, 0.f, 0.f};
#pragma unroll
            for (int kt = 0; kt < 4; kt++) {
                short8 a =
                    *(const short8*)&bufW[(16 * rt + fr) * 136 + kt * 32 + fq * 8];
                short8 bb =
                    *(const short8*)&bufK[(16 * jt + fr) * 136 + kt * 32 + fq * 8];
                acc1 = __builtin_amdgcn_mfma_f32_16x16x32_bf16(a, bb, acc1, 0, 0, 0);
            }
            const int j = 16 * jt + fr;
#pragma unroll
            for (int reg = 0; reg < 4; reg++) {
                const int nloc = 16 * rt + fq * 4 + reg;
                float val = (j <= nloc) ? acc1[reg] : 0.f;
                bufP[nloc * 40 + j] = (short)f2bf(val);
            }
        }
        __syncthreads(); // (3) Pb ready

        // ---- P2b: out += P @ V (K=32)
        {
            short8 a = *(const short8*)&bufP[(16 * rt + fr) * 40 + fq * 8];
            short8 bb = *(const short8*)&vT[(16 * js + fr) * 40 + fq * 8];
            acc2 = __builtin_amdgcn_mfma_f32_16x16x32_bf16(a, bb, acc2, 0, 0, 0);
        }

        // ---- epilogue
#pragma unroll
        for (int reg = 0; reg < 4; reg++) {
            out[(rowstart + 16 * rt + fq * 4 + reg) * D + 16 * js + fr] =
                acc2[reg];
        }
    }
}

extern "C" void kernel_launch(void* const* d_in, const int* in_sizes, int n_in,
                              void* d_out, int out_size, void* d_ws, size_t ws_size,
                              hipStream_t stream) {
    const float* q = (const float*)d_in[0];
    const float* k = (const float*)d_in[1];
    const float* v = (const float*)d_in[2];
    const float* proj = (const float*)d_in[3];
    float* out = (float*)d_out;

    // workspace: [0,64) barrier counters (memset each iteration);
    // then kpart 128KB fp32; qpb/kpb 2MB bf16 each; Gpb 4MB bf16;
    // zpre 128KB fp32; S0pre 4MB bf16 (s-granular)
    unsigned* bar = (unsigned*)d_ws;
    float* kpart = (float*)((char*)d_ws + 64);                   // H*32*M
    unsigned short* qpb = (unsigned short*)(kpart + H * 32 * M); // H*N*M
    unsigned short* kpb = qpb + H * N * M;                       // H*N*M
    unsigned short* Gpb = kpb + H * N * M;                       // H*32*M*D
    float* zpre = (float*)(Gpb + H * 32 * M * D);                // H*32*M
    unsigned short* S0pre = (unsigned short*)(zpre + H * 32 * M); // H*32*M*D

    hipMemsetAsync(d_ws, 0, 64, stream); // zero barrier counters (captured)
    k_fused<<<dim3(NBLK), dim3(512), 0, stream>>>(q, k, proj, v, qpb, kpb, Gpb,
                                                  kpart, zpre, S0pre, out, bar);
}

// Round 5
// 77.205 us; speedup vs baseline: 1.6140x; 1.6140x over previous
//
#include <hip/hip_runtime.h>

// Performer causal linear attention (generalized relu kernel), fp32 in/out.
// B=1, H=8, N=1024, D=64, M=128. Sub-block formulation, S=32 rows/block:
//   qp = relu(norm * q @ proj^T) + eps ; kp likewise
//   Z  = cumsum_n kp ; W = qp / Z
//   out_s = W_s @ S0_s + tril(W_s @ Kp_s^T) @ V_s ; S0_s = prefix of Kp^T V
// R17: revert R16's fused grid-barrier design (measured: 2 manual barriers
// with agent-scope fences cost ~+27us vs kernel boundaries — per-XCD L2
// writeback/invalidate per block). Back to 3 kernels (R15) with latency
// fixes: (1) k_prefix 64->256 blocks (1 elem-chain/thread, same fp32 order),
// (2) k_attn staging via 16B short8 loads, all global loads front-loaded
// before LDS writes, (3) k_projg 16B qpb/kpb writeout + early q/k/v loads.
static constexpr int H = 8, N = 1024, D = 64, M = 128;
static constexpr float EPS = 1e-3f;
static constexpr float NORM = 0.35355339059327373f; // 64^-0.25

typedef __attribute__((ext_vector_type(8))) short short8;
typedef __attribute__((ext_vector_type(4))) float f32x4;

__device__ inline unsigned short f2bf(float x) {
    unsigned u = __float_as_uint(x);
    return (unsigned short)((u + 0x7fffu + ((u >> 16) & 1u)) >> 16);
}
__device__ inline float bf2f(unsigned short u) {
    return __uint_as_float(((unsigned)u) << 16);
}
__device__ inline ushort4 pack4(float4 g) {
    return (ushort4){f2bf(g.x), f2bf(g.y), f2bf(g.z), f2bf(g.w)};
}

// -------- K1: qpb/kpb = bf16(relu(norm x @ proj^T)+eps), Gpb, kpart.
// grid (32 rblk, 8 h), 512 thr. One block: 32 rows of BOTH q and k.
__global__ __launch_bounds__(512) void k_projg(const float* __restrict__ q,
                                               const float* __restrict__ k,
                                               const float* __restrict__ proj,
                                               const float* __restrict__ v,
                                               unsigned short* __restrict__ qpb,
                                               unsigned short* __restrict__ kpb,
                                               unsigned short* __restrict__ Gpb,
                                               float* __restrict__ kpart) {
    __shared__ __align__(16) short smem[30208]; // 60.4 KB
    short* projb = smem;         // [m 128][72] B-operand
    short* xb = smem + 9216;     // [r 64][72] A-operand (q rows 0-31, k 32-63)
    short* obuf = smem + 13824;  // [64][136] out tile / later [128][68] G
    short* kpT = smem + 22528;   // [m 128][40] A-operand for G
    short* vT = smem + 27648;    // [e 64][40] B-operand for G
    const int tid = threadIdx.x;
    const int rblk = blockIdx.x;
    const int h = blockIdx.y;
    const int rowbase = h * N + rblk * 32;
    const int lane = tid & 63, wv = tid >> 6;
    const int rt = wv & 3, mh = wv >> 2;
    const int fr = lane & 15, fq = lane >> 4;

    // ---- front-load own q/k/v global loads (latency overlaps proj loop)
    {
        int r = tid >> 4, dq = tid & 15;
        float4 g = *(const float4*)&q[(rowbase + r) * D + dq * 4];
        float4 gk = *(const float4*)&k[(rowbase + r) * D + dq * 4];
        int rv = tid & 31, e4 = (tid >> 5) * 4;
        float4 gv = *(const float4*)&v[(rowbase + rv) * D + e4];
        g.x *= NORM; g.y *= NORM; g.z *= NORM; g.w *= NORM;
        *(ushort4*)&xb[r * 72 + dq * 4] = pack4(g);
        gk.x *= NORM; gk.y *= NORM; gk.z *= NORM; gk.w *= NORM;
        *(ushort4*)&xb[(32 + r) * 72 + dq * 4] = pack4(gk);
        vT[(e4 + 0) * 40 + rv] = (short)f2bf(gv.x);
        vT[(e4 + 1) * 40 + rv] = (short)f2bf(gv.y);
        vT[(e4 + 2) * 40 + rv] = (short)f2bf(gv.z);
        vT[(e4 + 3) * 40 + rv] = (short)f2bf(gv.w);
    }
    for (int i4 = tid; i4 < 2048; i4 += 512) {
        int m = i4 >> 4, dq = i4 & 15;
        *(ushort4*)&projb[m * 72 + dq * 4] = pack4(*(const float4*)&proj[i4 * 4]);
    }
    __syncthreads();

    f32x4 accp[4];
#pragma unroll
    for (int i = 0; i < 4; i++) accp[i] = (f32x4){0.f, 0.f, 0.f, 0.f};
#pragma unroll
    for (int kt = 0; kt < 2; kt++) {
        short8 a = *(const short8*)&xb[(16 * rt + fr) * 72 + kt * 32 + fq * 8];
#pragma unroll
        for (int i = 0; i < 4; i++) {
            const int mt = mh * 4 + i;
            short8 bb = *(const short8*)&projb[(16 * mt + fr) * 72 + kt * 32 + fq * 8];
            accp[i] = __builtin_amdgcn_mfma_f32_16x16x32_bf16(a, bb, accp[i], 0, 0, 0);
        }
    }
#pragma unroll
    for (int i = 0; i < 4; i++) {
        const int mt = mh * 4 + i;
#pragma unroll
        for (int reg = 0; reg < 4; reg++) {
            const int r = 16 * rt + fq * 4 + reg;
            const int m = 16 * mt + fr;
            unsigned short bv = f2bf(fmaxf(accp[i][reg], 0.f) + EPS);
            obuf[r * 136 + m] = (short)bv;
            if (rt >= 2) kpT[m * 40 + (r - 32)] = (short)bv;
        }
    }
    __syncthreads();

    // ---- writeout qp/kp as 16B short8 (row strides 272B / 256B, aligned)
    for (int i = tid; i < 1024; i += 512) {
        int r = i >> 4, cu8 = i & 15;
        short8 val = *(const short8*)&obuf[r * 136 + cu8 * 8];
        unsigned short* g = (r < 32) ? &qpb[(rowbase + r) * M + cu8 * 8]
                                     : &kpb[(rowbase + r - 32) * M + cu8 * 8];
        *(short8*)g = val;
    }
    const int gb = h * 32 + rblk;
    if (tid < 128) {
        float ks = 0.f;
#pragma unroll 8
        for (int r = 0; r < 32; r++) ks += bf2f((unsigned short)kpT[tid * 40 + r]);
        kpart[gb * M + tid] = ks;
    }
    __syncthreads();

    f32x4 gacc[4];
#pragma unroll
    for (int et = 0; et < 4; et++) gacc[et] = (f32x4){0.f, 0.f, 0.f, 0.f};
    {
        short8 a = *(const short8*)&kpT[(16 * wv + fr) * 40 + fq * 8];
#pragma unroll
        for (int et = 0; et < 4; et++) {
            short8 bb = *(const short8*)&vT[(16 * et + fr) * 40 + fq * 8];
            gacc[et] = __builtin_amdgcn_mfma_f32_16x16x32_bf16(a, bb, gacc[et], 0, 0, 0);
        }
    }
#pragma unroll
    for (int et = 0; et < 4; et++)
#pragma unroll
        for (int reg = 0; reg < 4; reg++) {
            const int m = 16 * wv + fq * 4 + reg;
            obuf[m * 68 + 16 * et + fr] = (short)f2bf(gacc[et][reg]);
        }
    __syncthreads();
    for (int i = tid; i < 2048; i += 512) {
        int m = i >> 4, e4 = (i & 15) * 4;
        *(ushort4*)&Gpb[(gb * M + m) * D + e4] = *(const ushort4*)&obuf[m * 68 + e4];
    }
}

// -------- K1.5 (R17): s-granular prefixes, 256 blocks x 256 thr.
// grid (h*32+seg); each thread owns ONE element chain over s (fp32, s-order
// identical to R15 -> bit-identical S0pre). zpre by seg==0 blocks.
__global__ __launch_bounds__(256) void k_prefix(const float* __restrict__ kpart,
                                                const unsigned short* __restrict__ Gpb,
                                                float* __restrict__ zpre,
                                                unsigned short* __restrict__ S0pre) {
    const int h = blockIdx.x >> 5, seg = blockIdx.x & 31;
    const int tid = threadIdx.x;
    const int eb = seg * 256 + tid;
    float a = 0.f;
#pragma unroll 8
    for (int s = 0; s < 32; s++) {
        S0pre[(h * 32 + s) * (M * D) + eb] = f2bf(a);
        a += bf2f(Gpb[(h * 32 + s) * (M * D) + eb]);
    }
    if (seg == 0 && tid < 128) {
        float z = 0.f;
#pragma unroll 8
        for (int s = 0; s < 32; s++) {
            zpre[(h * 32 + s) * M + tid] = z;
            z += kpart[(h * 32 + s) * M + tid];
        }
    }
}

// -------- K2: grid (256), 512 thr. Every block identical: 32 output rows.
// out = W @ S0pre[s] + tril(W @ Kp_own^T) @ V_own.
// R17: 16B staged loads, all global loads front-loaded before LDS writes.
__global__ __launch_bounds__(512) void k_attn(const unsigned short* __restrict__ qpb,
                                              const unsigned short* __restrict__ kpb,
                                              const float* __restrict__ zpre,
                                              const unsigned short* __restrict__ S0pre,
                                              const float* __restrict__ v,
                                              float* __restrict__ out) {
    __shared__ __align__(16) short smem[25600]; // 51.2 KB
    short* bufW = smem;          // W  [32 n][136]
    short* bufK = smem + 4352;   // Kp [32 j][136]
    short* bufQ = smem + 8704;   // qp [32 n][136]
    short* s0t  = smem + 13056;  // S0^T [64 e][136] (m in columns)
    short* vT   = smem + 21760;  // V^T  [64 e][40]  (j in columns)
    short* bufP = smem + 24320;  // Pb   [32 n][40]  (j in columns)
    const int tid = threadIdx.x;
    const int b = blockIdx.x;
    const int h = b >> 5, s = b & 31;
    const int rowstart = h * N + s * 32;
    const int lane = tid & 63, wv = tid >> 6;
    const int rt = wv & 1, js = wv >> 1;
    const int fr = lane & 15, fq = lane >> 4;

    // ---- straight-line global loads (all issue before any LDS write)
    const int sj = tid >> 4, smu = tid & 15; // kp/qp: row sj, 8-ushort grp smu
    short8 kpre = *(const short8*)&kpb[(rowstart + sj) * M + smu * 8];
    short8 qpre = *(const short8*)&qpb[(rowstart + sj) * M + smu * 8];
    const int pm = tid >> 2, peb = (tid & 3) * 16;
    const unsigned short* s0src = &S0pre[(h * 32 + s) * (M * D) + pm * D + peb];
    short8 s0a = *(const short8*)&s0src[0];
    short8 s0b = *(const short8*)&s0src[8];
    const int ve4 = (tid & 15) * 4;
    float4 gv = *(const float4*)&v[(rowstart + sj) * D + ve4];
    float zinit = 0.f;
    if (tid < 128) zinit = zpre[(h * 32 + s) * M + tid];

    // ---- LDS writes
    *(short8*)&bufK[sj * 136 + smu * 8] = kpre;
    *(short8*)&bufQ[sj * 136 + smu * 8] = qpre;
#pragma unroll
    for (int j = 0; j < 8; j++) {
        s0t[(peb + j) * 136 + pm] = s0a[j];
        s0t[(peb + 8 + j) * 136 + pm] = s0b[j];
    }
    vT[(ve4 + 0) * 40 + sj] = (short)f2bf(gv.x);
    vT[(ve4 + 1) * 40 + sj] = (short)f2bf(gv.y);
    vT[(ve4 + 2) * 40 + sj] = (short)f2bf(gv.z);
    vT[(ve4 + 3) * 40 + sj] = (short)f2bf(gv.w);
    __syncthreads(); // (1)

    // ---- z-scan -> W (tid<128, seeded from zpre)
    if (tid < 128) {
        const int m = tid;
        float z = zinit;
#pragma unroll 8
        for (int r = 0; r < 32; r++) {
            z += bf2f((unsigned short)bufK[r * 136 + m]);
            bufW[r * 136 + m] = (short)f2bf(
                bf2f((unsigned short)bufQ[r * 136 + m]) * __builtin_amdgcn_rcpf(z));
        }
    }
    __syncthreads(); // (2) W ready

    // ---- P2a: out = W @ S0 (K=128) — all 8 waves, tile (rt, js)
    f32x4 acc2 = (f32x4){0.f, 0.f, 0.f, 0.f};
#pragma unroll
    for (int kt = 0; kt < 4; kt++) {
        short8 a = *(const short8*)&bufW[(16 * rt + fr) * 136 + kt * 32 + fq * 8];
        short8 bb = *(const short8*)&s0t[(16 * js + fr) * 136 + kt * 32 + fq * 8];
        acc2 = __builtin_amdgcn_mfma_f32_16x16x32_bf16(a, bb, acc2, 0, 0, 0);
    }
    // ---- P1: Pb = tril(W @ Kp^T) — waves 0..3 only, tile (rt, jt)
    if (wv < 4) {
        const int jt = wv >> 1;
        f32x4 acc1 = (f32x4){0.f, 0.f, 0.f, 0.f};
#pragma unroll
        for (int kt = 0; kt < 4; kt++) {
            short8 a = *(const short8*)&bufW[(16 * rt + fr) * 136 + kt * 32 + fq * 8];
            short8 bb = *(const short8*)&bufK[(16 * jt + fr) * 136 + kt * 32 + fq * 8];
            acc1 = __builtin_amdgcn_mfma_f32_16x16x32_bf16(a, bb, acc1, 0, 0, 0);
        }
        const int j = 16 * jt + fr;
#pragma unroll
        for (int reg = 0; reg < 4; reg++) {
            const int nloc = 16 * rt + fq * 4 + reg;
            float val = (j <= nloc) ? acc1[reg] : 0.f;
            bufP[nloc * 40 + j] = (short)f2bf(val);
        }
    }
    __syncthreads(); // (3) Pb ready

    // ---- P2b: out += P @ V (K=32)
    {
        short8 a = *(const short8*)&bufP[(16 * rt + fr) * 40 + fq * 8];
        short8 bb = *(const short8*)&vT[(16 * js + fr) * 40 + fq * 8];
        acc2 = __builtin_amdgcn_mfma_f32_16x16x32_bf16(a, bb, acc2, 0, 0, 0);
    }

    // ---- epilogue
#pragma unroll
    for (int reg = 0; reg < 4; reg++) {
        out[(rowstart + 16 * rt + fq * 4 + reg) * D + 16 * js + fr] = acc2[reg];
    }
}

extern "C" void kernel_launch(void* const* d_in, const int* in_sizes, int n_in,
                              void* d_out, int out_size, void* d_ws, size_t ws_size,
                              hipStream_t stream) {
    const float* q = (const float*)d_in[0];
    const float* k = (const float*)d_in[1];
    const float* v = (const float*)d_in[2];
    const float* proj = (const float*)d_in[3];
    float* out = (float*)d_out;

    // workspace: kpart 128KB fp32; qpb/kpb 2MB bf16 each; Gpb 4MB bf16;
    // zpre 128KB fp32; S0pre 4MB bf16 (s-granular)
    float* ws = (float*)d_ws;
    float* kpart = ws;                                           // H*32*M
    unsigned short* qpb = (unsigned short*)(kpart + H * 32 * M); // H*N*M
    unsigned short* kpb = qpb + H * N * M;                       // H*N*M
    unsigned short* Gpb = kpb + H * N * M;                       // H*32*M*D
    float* zpre = (float*)(Gpb + H * 32 * M * D);                // H*32*M
    unsigned short* S0pre = (unsigned short*)(zpre + H * 32 * M); // H*32*M*D

    k_projg<<<dim3(32, H), 512, 0, stream>>>(q, k, proj, v, qpb, kpb, Gpb,
                                             kpart);
    k_prefix<<<dim3(256), 256, 0, stream>>>(kpart, Gpb, zpre, S0pre);
    k_attn<<<dim3(H * 32), 512, 0, stream>>>(qpb, kpb, zpre, S0pre, v, out);
}

// Round 6
// 75.562 us; speedup vs baseline: 1.6491x; 1.0217x over previous
//
#include <hip/hip_runtime.h>

// Performer causal linear attention (generalized relu kernel), fp32 in/out.
// B=1, H=8, N=1024, D=64, M=128. Sub-block formulation, S=32 rows/block:
//   qp = relu(norm * q @ proj^T) + eps ; kp likewise
//   Z  = cumsum_n kp ; W = qp / Z
//   out_s = W_s @ S0_s + tril(W_s @ Kp_s^T) @ V_s ; S0_s = prefix of Kp^T V
// R18 (on R17): shorten serial chains.
//  (1) k_prefix: hoist all 32 G loads (and 32 kpart loads) into registers
//      before the fp32 prefix chain — load latency leaves the serial path;
//      chain order unchanged -> bit-identical S0pre/zpre.
//  (2) k_attn: z-scan 4-way parallel per column (thread = m*4+q): each
//      thread sums its 8 rows in order, 4-lane __shfl_up scan for quarter
//      offsets, then 8 W rows. Serial depth 32 -> ~10. (fp32 reassoc of
//      positive values only; ~1e-7 rel perturbation, well under bf16 noise.)
static constexpr int H = 8, N = 1024, D = 64, M = 128;
static constexpr float EPS = 1e-3f;
static constexpr float NORM = 0.35355339059327373f; // 64^-0.25

typedef __attribute__((ext_vector_type(8))) short short8;
typedef __attribute__((ext_vector_type(4))) float f32x4;

__device__ inline unsigned short f2bf(float x) {
    unsigned u = __float_as_uint(x);
    return (unsigned short)((u + 0x7fffu + ((u >> 16) & 1u)) >> 16);
}
__device__ inline float bf2f(unsigned short u) {
    return __uint_as_float(((unsigned)u) << 16);
}
__device__ inline ushort4 pack4(float4 g) {
    return (ushort4){f2bf(g.x), f2bf(g.y), f2bf(g.z), f2bf(g.w)};
}

// -------- K1: qpb/kpb = bf16(relu(norm x @ proj^T)+eps), Gpb, kpart.
// grid (32 rblk, 8 h), 512 thr. One block: 32 rows of BOTH q and k.
// (identical to R17)
__global__ __launch_bounds__(512) void k_projg(const float* __restrict__ q,
                                               const float* __restrict__ k,
                                               const float* __restrict__ proj,
                                               const float* __restrict__ v,
                                               unsigned short* __restrict__ qpb,
                                               unsigned short* __restrict__ kpb,
                                               unsigned short* __restrict__ Gpb,
                                               float* __restrict__ kpart) {
    __shared__ __align__(16) short smem[30208]; // 60.4 KB
    short* projb = smem;         // [m 128][72] B-operand
    short* xb = smem + 9216;     // [r 64][72] A-operand (q rows 0-31, k 32-63)
    short* obuf = smem + 13824;  // [64][136] out tile / later [128][68] G
    short* kpT = smem + 22528;   // [m 128][40] A-operand for G
    short* vT = smem + 27648;    // [e 64][40] B-operand for G
    const int tid = threadIdx.x;
    const int rblk = blockIdx.x;
    const int h = blockIdx.y;
    const int rowbase = h * N + rblk * 32;
    const int lane = tid & 63, wv = tid >> 6;
    const int rt = wv & 3, mh = wv >> 2;
    const int fr = lane & 15, fq = lane >> 4;

    // ---- front-load own q/k/v global loads (latency overlaps proj loop)
    {
        int r = tid >> 4, dq = tid & 15;
        float4 g = *(const float4*)&q[(rowbase + r) * D + dq * 4];
        float4 gk = *(const float4*)&k[(rowbase + r) * D + dq * 4];
        int rv = tid & 31, e4 = (tid >> 5) * 4;
        float4 gv = *(const float4*)&v[(rowbase + rv) * D + e4];
        g.x *= NORM; g.y *= NORM; g.z *= NORM; g.w *= NORM;
        *(ushort4*)&xb[r * 72 + dq * 4] = pack4(g);
        gk.x *= NORM; gk.y *= NORM; gk.z *= NORM; gk.w *= NORM;
        *(ushort4*)&xb[(32 + r) * 72 + dq * 4] = pack4(gk);
        vT[(e4 + 0) * 40 + rv] = (short)f2bf(gv.x);
        vT[(e4 + 1) * 40 + rv] = (short)f2bf(gv.y);
        vT[(e4 + 2) * 40 + rv] = (short)f2bf(gv.z);
        vT[(e4 + 3) * 40 + rv] = (short)f2bf(gv.w);
    }
    for (int i4 = tid; i4 < 2048; i4 += 512) {
        int m = i4 >> 4, dq = i4 & 15;
        *(ushort4*)&projb[m * 72 + dq * 4] = pack4(*(const float4*)&proj[i4 * 4]);
    }
    __syncthreads();

    f32x4 accp[4];
#pragma unroll
    for (int i = 0; i < 4; i++) accp[i] = (f32x4){0.f, 0.f, 0.f, 0.f};
#pragma unroll
    for (int kt = 0; kt < 2; kt++) {
        short8 a = *(const short8*)&xb[(16 * rt + fr) * 72 + kt * 32 + fq * 8];
#pragma unroll
        for (int i = 0; i < 4; i++) {
            const int mt = mh * 4 + i;
            short8 bb = *(const short8*)&projb[(16 * mt + fr) * 72 + kt * 32 + fq * 8];
            accp[i] = __builtin_amdgcn_mfma_f32_16x16x32_bf16(a, bb, accp[i], 0, 0, 0);
        }
    }
#pragma unroll
    for (int i = 0; i < 4; i++) {
        const int mt = mh * 4 + i;
#pragma unroll
        for (int reg = 0; reg < 4; reg++) {
            const int r = 16 * rt + fq * 4 + reg;
            const int m = 16 * mt + fr;
            unsigned short bv = f2bf(fmaxf(accp[i][reg], 0.f) + EPS);
            obuf[r * 136 + m] = (short)bv;
            if (rt >= 2) kpT[m * 40 + (r - 32)] = (short)bv;
        }
    }
    __syncthreads();

    // ---- writeout qp/kp as 16B short8 (row strides 272B / 256B, aligned)
    for (int i = tid; i < 1024; i += 512) {
        int r = i >> 4, cu8 = i & 15;
        short8 val = *(const short8*)&obuf[r * 136 + cu8 * 8];
        unsigned short* g = (r < 32) ? &qpb[(rowbase + r) * M + cu8 * 8]
                                     : &kpb[(rowbase + r - 32) * M + cu8 * 8];
        *(short8*)g = val;
    }
    const int gb = h * 32 + rblk;
    if (tid < 128) {
        float ks = 0.f;
#pragma unroll 8
        for (int r = 0; r < 32; r++) ks += bf2f((unsigned short)kpT[tid * 40 + r]);
        kpart[gb * M + tid] = ks;
    }
    __syncthreads();

    f32x4 gacc[4];
#pragma unroll
    for (int et = 0; et < 4; et++) gacc[et] = (f32x4){0.f, 0.f, 0.f, 0.f};
    {
        short8 a = *(const short8*)&kpT[(16 * wv + fr) * 40 + fq * 8];
#pragma unroll
        for (int et = 0; et < 4; et++) {
            short8 bb = *(const short8*)&vT[(16 * et + fr) * 40 + fq * 8];
            gacc[et] = __builtin_amdgcn_mfma_f32_16x16x32_bf16(a, bb, gacc[et], 0, 0, 0);
        }
    }
#pragma unroll
    for (int et = 0; et < 4; et++)
#pragma unroll
        for (int reg = 0; reg < 4; reg++) {
            const int m = 16 * wv + fq * 4 + reg;
            obuf[m * 68 + 16 * et + fr] = (short)f2bf(gacc[et][reg]);
        }
    __syncthreads();
    for (int i = tid; i < 2048; i += 512) {
        int m = i >> 4, e4 = (i & 15) * 4;
        *(ushort4*)&Gpb[(gb * M + m) * D + e4] = *(const ushort4*)&obuf[m * 68 + e4];
    }
}

// -------- K1.5 (R18): s-granular prefixes, 256 blocks x 256 thr.
// All 32 loads hoisted into registers (one vmcnt wait), then the fp32
// chain (order identical to R17 -> bit-identical), then 32 stores.
__global__ __launch_bounds__(256) void k_prefix(const float* __restrict__ kpart,
                                                const unsigned short* __restrict__ Gpb,
                                                float* __restrict__ zpre,
                                                unsigned short* __restrict__ S0pre) {
    const int h = blockIdx.x >> 5, seg = blockIdx.x & 31;
    const int tid = threadIdx.x;
    const int eb = seg * 256 + tid;
    float g[32];
#pragma unroll
    for (int s = 0; s < 32; s++)
        g[s] = bf2f(Gpb[(h * 32 + s) * (M * D) + eb]);
    float a = 0.f;
    unsigned short o[32];
#pragma unroll
    for (int s = 0; s < 32; s++) {
        o[s] = f2bf(a);
        a += g[s];
    }
#pragma unroll
    for (int s = 0; s < 32; s++)
        S0pre[(h * 32 + s) * (M * D) + eb] = o[s];

    if (seg == 0 && tid < 128) {
        float kv[32];
#pragma unroll
        for (int s = 0; s < 32; s++) kv[s] = kpart[(h * 32 + s) * M + tid];
        float z = 0.f;
        float zo[32];
#pragma unroll
        for (int s = 0; s < 32; s++) {
            zo[s] = z;
            z += kv[s];
        }
#pragma unroll
        for (int s = 0; s < 32; s++)
            zpre[(h * 32 + s) * M + tid] = zo[s];
    }
}

// -------- K2: grid (256), 512 thr. Every block identical: 32 output rows.
// out = W @ S0pre[s] + tril(W @ Kp_own^T) @ V_own.
// R18: z-scan 4-way parallel (thread = m*4+q, shfl_up quarter scan).
__global__ __launch_bounds__(512) void k_attn(const unsigned short* __restrict__ qpb,
                                              const unsigned short* __restrict__ kpb,
                                              const float* __restrict__ zpre,
                                              const unsigned short* __restrict__ S0pre,
                                              const float* __restrict__ v,
                                              float* __restrict__ out) {
    __shared__ __align__(16) short smem[25600]; // 51.2 KB
    short* bufW = smem;          // W  [32 n][136]
    short* bufK = smem + 4352;   // Kp [32 j][136]
    short* bufQ = smem + 8704;   // qp [32 n][136]
    short* s0t  = smem + 13056;  // S0^T [64 e][136] (m in columns)
    short* vT   = smem + 21760;  // V^T  [64 e][40]  (j in columns)
    short* bufP = smem + 24320;  // Pb   [32 n][40]  (j in columns)
    const int tid = threadIdx.x;
    const int b = blockIdx.x;
    const int h = b >> 5, s = b & 31;
    const int rowstart = h * N + s * 32;
    const int lane = tid & 63, wv = tid >> 6;
    const int rt = wv & 1, js = wv >> 1;
    const int fr = lane & 15, fq = lane >> 4;

    // ---- straight-line global loads (all issue before any LDS write)
    const int sj = tid >> 4, smu = tid & 15; // kp/qp: row sj, 8-ushort grp smu
    short8 kpre = *(const short8*)&kpb[(rowstart + sj) * M + smu * 8];
    short8 qpre = *(const short8*)&qpb[(rowstart + sj) * M + smu * 8];
    const int pm = tid >> 2, peb = (tid & 3) * 16;
    const unsigned short* s0src = &S0pre[(h * 32 + s) * (M * D) + pm * D + peb];
    short8 s0a = *(const short8*)&s0src[0];
    short8 s0b = *(const short8*)&s0src[8];
    const int ve4 = (tid & 15) * 4;
    float4 gv = *(const float4*)&v[(rowstart + sj) * D + ve4];
    const float zinit = zpre[(h * 32 + s) * M + (tid >> 2)];

    // ---- LDS writes
    *(short8*)&bufK[sj * 136 + smu * 8] = kpre;
    *(short8*)&bufQ[sj * 136 + smu * 8] = qpre;
#pragma unroll
    for (int j = 0; j < 8; j++) {
        s0t[(peb + j) * 136 + pm] = s0a[j];
        s0t[(peb + 8 + j) * 136 + pm] = s0b[j];
    }
    vT[(ve4 + 0) * 40 + sj] = (short)f2bf(gv.x);
    vT[(ve4 + 1) * 40 + sj] = (short)f2bf(gv.y);
    vT[(ve4 + 2) * 40 + sj] = (short)f2bf(gv.z);
    vT[(ve4 + 3) * 40 + sj] = (short)f2bf(gv.w);
    __syncthreads(); // (1)

    // ---- z-scan -> W, 4-way parallel: thread (zm = tid>>2, qr = tid&3)
    {
        const int zm = tid >> 2, qr = tid & 3, r0 = qr * 8;
        float kv[8];
        float part = 0.f;
#pragma unroll
        for (int r = 0; r < 8; r++) {
            kv[r] = bf2f((unsigned short)bufK[(r0 + r) * 136 + zm]);
            part += kv[r];
        }
        float incl = part, t;
        t = __shfl_up(incl, 1, 4); if (qr >= 1) incl += t;
        t = __shfl_up(incl, 2, 4); if (qr >= 2) incl += t;
        t = __shfl_up(incl, 1, 4); // = inclusive sum of quarter qr-1
        float z = zinit + ((qr == 0) ? 0.f : t);
#pragma unroll
        for (int r = 0; r < 8; r++) {
            const int rr = r0 + r;
            z += kv[r];
            bufW[rr * 136 + zm] = (short)f2bf(
                bf2f((unsigned short)bufQ[rr * 136 + zm]) *
                __builtin_amdgcn_rcpf(z));
        }
    }
    __syncthreads(); // (2) W ready

    // ---- P2a: out = W @ S0 (K=128) — all 8 waves, tile (rt, js)
    f32x4 acc2 = (f32x4){0.f, 0.f, 0.f, 0.f};
#pragma unroll
    for (int kt = 0; kt < 4; kt++) {
        short8 a = *(const short8*)&bufW[(16 * rt + fr) * 136 + kt * 32 + fq * 8];
        short8 bb = *(const short8*)&s0t[(16 * js + fr) * 136 + kt * 32 + fq * 8];
        acc2 = __builtin_amdgcn_mfma_f32_16x16x32_bf16(a, bb, acc2, 0, 0, 0);
    }
    // ---- P1: Pb = tril(W @ Kp^T) — waves 0..3 only, tile (rt, jt)
    if (wv < 4) {
        const int jt = wv >> 1;
        f32x4 acc1 = (f32x4){0.f, 0.f, 0.f, 0.f};
#pragma unroll
        for (int kt = 0; kt < 4; kt++) {
            short8 a = *(const short8*)&bufW[(16 * rt + fr) * 136 + kt * 32 + fq * 8];
            short8 bb = *(const short8*)&bufK[(16 * jt + fr) * 136 + kt * 32 + fq * 8];
            acc1 = __builtin_amdgcn_mfma_f32_16x16x32_bf16(a, bb, acc1, 0, 0, 0);
        }
        const int j = 16 * jt + fr;
#pragma unroll
        for (int reg = 0; reg < 4; reg++) {
            const int nloc = 16 * rt + fq * 4 + reg;
            float val = (j <= nloc) ? acc1[reg] : 0.f;
            bufP[nloc * 40 + j] = (short)f2bf(val);
        }
    }
    __syncthreads(); // (3) Pb ready

    // ---- P2b: out += P @ V (K=32)
    {
        short8 a = *(const short8*)&bufP[(16 * rt + fr) * 40 + fq * 8];
        short8 bb = *(const short8*)&vT[(16 * js + fr) * 40 + fq * 8];
        acc2 = __builtin_amdgcn_mfma_f32_16x16x32_bf16(a, bb, acc2, 0, 0, 0);
    }

    // ---- epilogue
#pragma unroll
    for (int reg = 0; reg < 4; reg++) {
        out[(rowstart + 16 * rt + fq * 4 + reg) * D + 16 * js + fr] = acc2[reg];
    }
}

extern "C" void kernel_launch(void* const* d_in, const int* in_sizes, int n_in,
                              void* d_out, int out_size, void* d_ws, size_t ws_size,
                              hipStream_t stream) {
    const float* q = (const float*)d_in[0];
    const float* k = (const float*)d_in[1];
    const float* v = (const float*)d_in[2];
    const float* proj = (const float*)d_in[3];
    float* out = (float*)d_out;

    // workspace: kpart 128KB fp32; qpb/kpb 2MB bf16 each; Gpb 4MB bf16;
    // zpre 128KB fp32; S0pre 4MB bf16 (s-granular)
    float* ws = (float*)d_ws;
    float* kpart = ws;                                           // H*32*M
    unsigned short* qpb = (unsigned short*)(kpart + H * 32 * M); // H*N*M
    unsigned short* kpb = qpb + H * N * M;                       // H*N*M
    unsigned short* Gpb = kpb + H * N * M;                       // H*32*M*D
    float* zpre = (float*)(Gpb + H * 32 * M * D);                // H*32*M
    unsigned short* S0pre = (unsigned short*)(zpre + H * 32 * M); // H*32*M*D

    k_projg<<<dim3(32, H), 512, 0, stream>>>(q, k, proj, v, qpb, kpb, Gpb,
                                             kpart);
    k_prefix<<<dim3(256), 256, 0, stream>>>(kpart, Gpb, zpre, S0pre);
    k_attn<<<dim3(H * 32), 512, 0, stream>>>(qpb, kpb, zpre, S0pre, v, out);
}